// Round 3
// baseline (116.371 us; speedup 1.0000x reference)
//
#include <hip/hip_runtime.h>

// RGate: apply Rx(angle[i]) to every qubit of a 22-qubit statevector.
// Gate on qubit i pairs indices at stride 2^(21-i); all gates commute.
// TWO passes:
//   K1: bits 0-12  (8192-complex contiguous tile, 72.5 KB dynamic LDS)
//   K2: bits 13-21 (512 rows @ stride 8192 x 16-complex cols, 72 KB LDS)
// Register butterflies; LDS only for re-tiling. 2 blocks/CU each.

constexpr int NTOT = 1 << 22;   // 2^22 amplitudes

__device__ __forceinline__ void rotg(float& ar, float& ai, float& br, float& bi,
                                     float c, float s) {
    // a' = c*a - i*s*b ; b' = c*b - i*s*a
    float t0 = ar, t1 = ai, t2 = br, t3 = bi;
    ar = fmaf(c, t0,  s * t3);
    ai = fmaf(c, t1, -s * t2);
    br = fmaf(c, t2,  s * t1);
    bi = fmaf(c, t3, -s * t0);
}

__device__ __forceinline__ void rot4(float4& ar, float4& ai, float4& br, float4& bi,
                                     float c, float s) {
    rotg(ar.x, ai.x, br.x, bi.x, c, s);
    rotg(ar.y, ai.y, br.y, bi.y, c, s);
    rotg(ar.z, ai.z, br.z, bi.z, c, s);
    rotg(ar.w, ai.w, br.w, bi.w, c, s);
}

// two-level padded slot for K1 (keeps b128 pairs contiguous & 16B-aligned)
__device__ __forceinline__ int slotA(int i) { return i + 2 * (i >> 4) + 4 * (i >> 9); }

// K2 slot: row stride 18 float2, per-row 8B-granular chunk swizzle.
// lq must be 4-aligned chunk base; chunk occupies [base, base+4) within row.
__device__ __forceinline__ int slotB(int h, int lq) {
    const int z = (h ^ (h >> 3) ^ (h >> 6)) & 7;
    return h * 18 + ((lq + 2 * z) & 15);
}

// ---------------- K1: bits 0..12, tile = 8192 contiguous complex ----------
// 256 threads, 32 complex/thread.
//  arr1 (load):  i = t + 256*j       -> j = bits {8..12}, gates 8-12
//  arr2:         i = (t&31)+32*j+1024*(t>>5) -> j bits {5..9}, gates 5-7
//  arr3 (store): i = 32*t + r        -> r = bits {0..4}, gates 0-4, float4 out
__global__ __launch_bounds__(256) void rgate_lo(const float* __restrict__ xr,
                                                const float* __restrict__ xi,
                                                const float* __restrict__ ang,
                                                float* __restrict__ out) {
    extern __shared__ float4 svraw[];
    float2* sv = (float2*)svraw;
    __shared__ float csc[22], css[22];
    const int t  = threadIdx.x;
    const int g0 = blockIdx.x << 13;
    if (t < 22) { float a = 0.5f * ang[21 - t]; csc[t] = cosf(a); css[t] = sinf(a); }

    float ar[32], ai[32];
    #pragma unroll
    for (int j = 0; j < 32; ++j) {
        ar[j] = xr[g0 + t + (j << 8)];
        ai[j] = xi[g0 + t + (j << 8)];
    }
    __syncthreads();   // csc/css ready

    // gates 8..12 on j
    #pragma unroll
    for (int b = 0; b < 5; ++b) {
        const int m = 1 << b;
        const float c = csc[8 + b], s = css[8 + b];
        #pragma unroll
        for (int j = 0; j < 32; ++j)
            if (!(j & m)) rotg(ar[j], ai[j], ar[j | m], ai[j | m], c, s);
    }
    #pragma unroll
    for (int j = 0; j < 32; ++j)
        sv[slotA(t + (j << 8))] = make_float2(ar[j], ai[j]);
    __syncthreads();

    // arr2: gates 5..7
    {
        const int r = t & 31, hi = t >> 5;
        #pragma unroll
        for (int j = 0; j < 32; ++j) {
            float2 v = sv[slotA(r + (j << 5) + (hi << 10))];
            ar[j] = v.x; ai[j] = v.y;
        }
        #pragma unroll
        for (int b = 0; b < 3; ++b) {
            const int m = 1 << b;
            const float c = csc[5 + b], s = css[5 + b];
            #pragma unroll
            for (int j = 0; j < 32; ++j)
                if (!(j & m)) rotg(ar[j], ai[j], ar[j | m], ai[j | m], c, s);
        }
        #pragma unroll
        for (int j = 0; j < 32; ++j)
            sv[slotA(r + (j << 5) + (hi << 10))] = make_float2(ar[j], ai[j]);
    }
    __syncthreads();

    // arr3: gates 0..4, b128 LDS reads, float4 global stores
    {
        #pragma unroll
        for (int p = 0; p < 16; ++p) {
            float4 v = *(const float4*)&sv[slotA((t << 5) + 2 * p)];
            ar[2 * p]     = v.x; ai[2 * p]     = v.y;
            ar[2 * p + 1] = v.z; ai[2 * p + 1] = v.w;
        }
        #pragma unroll
        for (int b = 0; b < 5; ++b) {
            const int m = 1 << b;
            const float c = csc[b], s = css[b];
            #pragma unroll
            for (int j = 0; j < 32; ++j)
                if (!(j & m)) rotg(ar[j], ai[j], ar[j | m], ai[j | m], c, s);
        }
        float4* orp = (float4*)(out + g0 + (t << 5));
        float4* oip = (float4*)(out + NTOT + g0 + (t << 5));
        #pragma unroll
        for (int e = 0; e < 8; ++e) {
            orp[e] = make_float4(ar[4*e], ar[4*e+1], ar[4*e+2], ar[4*e+3]);
            oip[e] = make_float4(ai[4*e], ai[4*e+1], ai[4*e+2], ai[4*e+3]);
        }
    }
}

// ---------------- K2: bits 13..21, 512 rows (stride 8192) x 16 cols -------
// 256 threads, 32 complex/thread: q = t>>2 picks rows, (t&3)*4 picks l-chunk.
//  arr1 (load):  h = q + 64*j              -> j = h bits {6..8}, gates 19-21
//  arr2:         h = (q&7) + 8*j + 64*(q>>3) -> j = h bits {3..5}, gates 16-18
//  arr3 (store): h = j + 8*q               -> j = h bits {0..2}, gates 13-15
// All global accesses: 16 rows x 64 B contiguous per wave-instr.
__global__ __launch_bounds__(256) void rgate_hi(const float* __restrict__ ang,
                                                float* __restrict__ out) {
    extern __shared__ float4 svraw[];
    float2* sv = (float2*)svraw;
    __shared__ float csc[22], css[22];
    const int t     = threadIdx.x;
    const int q     = t >> 2;
    const int lq    = (t & 3) << 2;
    const int cbase = (blockIdx.x << 4) + lq;
    if (t < 22) { float a = 0.5f * ang[21 - t]; csc[t] = cosf(a); css[t] = sinf(a); }

    float4 vr[8], vi[8];
    #pragma unroll
    for (int j = 0; j < 8; ++j) {
        const int g = ((q + (j << 6)) << 13) + cbase;
        vr[j] = *(const float4*)(out + g);
        vi[j] = *(const float4*)(out + NTOT + g);
    }
    __syncthreads();   // csc/css ready

    // gates 19..21 on j
    #pragma unroll
    for (int b = 0; b < 3; ++b) {
        const int m = 1 << b;
        const float c = csc[19 + b], s = css[19 + b];
        #pragma unroll
        for (int j = 0; j < 8; ++j)
            if (!(j & m)) rot4(vr[j], vi[j], vr[j | m], vi[j | m], c, s);
    }
    #pragma unroll
    for (int j = 0; j < 8; ++j) {
        const int sb = slotB(q + (j << 6), lq);
        *(float4*)&sv[sb]     = make_float4(vr[j].x, vi[j].x, vr[j].y, vi[j].y);
        *(float4*)&sv[sb + 2] = make_float4(vr[j].z, vi[j].z, vr[j].w, vi[j].w);
    }
    __syncthreads();

    // arr2: gates 16..18
    {
        const int hbase = (q & 7) + ((q >> 3) << 6);
        #pragma unroll
        for (int j = 0; j < 8; ++j) {
            const int sb = slotB(hbase + (j << 3), lq);
            float4 v0 = *(const float4*)&sv[sb];
            float4 v1 = *(const float4*)&sv[sb + 2];
            vr[j] = make_float4(v0.x, v0.z, v1.x, v1.z);
            vi[j] = make_float4(v0.y, v0.w, v1.y, v1.w);
        }
        #pragma unroll
        for (int b = 0; b < 3; ++b) {
            const int m = 1 << b;
            const float c = csc[16 + b], s = css[16 + b];
            #pragma unroll
            for (int j = 0; j < 8; ++j)
                if (!(j & m)) rot4(vr[j], vi[j], vr[j | m], vi[j | m], c, s);
        }
        #pragma unroll
        for (int j = 0; j < 8; ++j) {
            const int sb = slotB(hbase + (j << 3), lq);
            *(float4*)&sv[sb]     = make_float4(vr[j].x, vi[j].x, vr[j].y, vi[j].y);
            *(float4*)&sv[sb + 2] = make_float4(vr[j].z, vi[j].z, vr[j].w, vi[j].w);
        }
    }
    __syncthreads();

    // arr3: gates 13..15, then coalesced float4 stores
    {
        #pragma unroll
        for (int j = 0; j < 8; ++j) {
            const int sb = slotB(j + (q << 3), lq);
            float4 v0 = *(const float4*)&sv[sb];
            float4 v1 = *(const float4*)&sv[sb + 2];
            vr[j] = make_float4(v0.x, v0.z, v1.x, v1.z);
            vi[j] = make_float4(v0.y, v0.w, v1.y, v1.w);
        }
        #pragma unroll
        for (int b = 0; b < 3; ++b) {
            const int m = 1 << b;
            const float c = csc[13 + b], s = css[13 + b];
            #pragma unroll
            for (int j = 0; j < 8; ++j)
                if (!(j & m)) rot4(vr[j], vi[j], vr[j | m], vi[j | m], c, s);
        }
        #pragma unroll
        for (int j = 0; j < 8; ++j) {
            const int g = ((j + (q << 3)) << 13) + cbase;
            *(float4*)(out + g)        = vr[j];
            *(float4*)(out + NTOT + g) = vi[j];
        }
    }
}

extern "C" void kernel_launch(void* const* d_in, const int* in_sizes, int n_in,
                              void* d_out, int out_size, void* d_ws, size_t ws_size,
                              hipStream_t stream) {
    const float* xr  = (const float*)d_in[0];
    const float* xi  = (const float*)d_in[1];
    const float* ang = (const float*)d_in[2];
    float* out = (float*)d_out;

    // K1 dynamic LDS: slotA(8191)+1 = 9274 float2 = 74192 B
    // K2 dynamic LDS: 512 rows * 18 float2 = 9216 float2 = 73728 B
    rgate_lo<<<512, 256, 74192, stream>>>(xr, xi, ang, out);   // bits 0-12
    rgate_hi<<<512, 256, 73728, stream>>>(ang, out);           // bits 13-21, in-place
}

// Round 4
// 113.175 us; speedup vs baseline: 1.0282x; 1.0282x over previous
//
#include <hip/hip_runtime.h>

// RGate: apply Rx(angle[i]) to every qubit of a 22-qubit statevector.
// Gate on qubit i pairs indices at stride 2^(21-i); all gates commute.
// TWO passes:
//   P1: bits 0-11  (4096-complex contiguous tile, 35 KB LDS, 4 blocks/CU)
//   P2: bits 12-21 (1024 rows @ stride 4096 x 16 cols, 139 KB LDS, 1024 thr)
// Register butterflies; LDS only for re-tiling. 3 barriers per kernel.

constexpr int NTOT = 1 << 22;   // 2^22 amplitudes

__device__ __forceinline__ void rotg(float& ar, float& ai, float& br, float& bi,
                                     float c, float s) {
    // a' = c*a - i*s*b ; b' = c*b - i*s*a
    float t0 = ar, t1 = ai, t2 = br, t3 = bi;
    ar = fmaf(c, t0,  s * t3);
    ai = fmaf(c, t1, -s * t2);
    br = fmaf(c, t2,  s * t1);
    bi = fmaf(c, t3, -s * t0);
}

__device__ __forceinline__ int padslot(int i) { return i + (i >> 4) + (i >> 8); }

// ---------------- P1: bits 0..11, tile = 4096 contiguous -------------------
// Block 256 threads, 16 complex/thread. Arrangements:
//  A1 (load):  idx = t + 256*j        -> reg bits {8..11}, gates k=8..11
//  A2:         idx = (t&15)+16*j+256*(t>>4) -> reg {4..7}, gates k=4..7
//  A3 (store): idx = j + 16*t         -> reg {0..3}, gates k=0..3, float4 out
__global__ __launch_bounds__(256, 4) void rgate_low(const float* __restrict__ xr,
                                                    const float* __restrict__ xi,
                                                    const float* __restrict__ ang,
                                                    float* __restrict__ out) {
    __shared__ float2 sv[4368];          // 4096 + pad (slot = i + (i>>4) + (i>>8))
    __shared__ float cs_c[22], cs_s[22];
    const int t  = threadIdx.x;
    const int g0 = blockIdx.x << 12;

    if (t < 22) { float a = 0.5f * ang[21 - t]; cs_c[t] = cosf(a); cs_s[t] = sinf(a); }

    float ar[16], ai[16];
    const float* xrp = xr + g0 + t;
    const float* xip = xi + g0 + t;
    #pragma unroll
    for (int j = 0; j < 16; ++j) {
        ar[j] = xrp[j << 8];
        ai[j] = xip[j << 8];
    }
    __syncthreads();   // cs ready

    // gates k=8..11 on register index
    #pragma unroll
    for (int b = 0; b < 4; ++b) {
        const int m = 1 << b;
        const float c = cs_c[8 + b], s = cs_s[8 + b];
        #pragma unroll
        for (int j = 0; j < 16; ++j)
            if (!(j & m)) rotg(ar[j], ai[j], ar[j | m], ai[j | m], c, s);
    }
    #pragma unroll
    for (int j = 0; j < 16; ++j)
        sv[padslot(t + (j << 8))] = make_float2(ar[j], ai[j]);
    __syncthreads();

    // A2: reg bits {4..7}
    {
        const int base2 = (t & 15) + ((t >> 4) << 8);
        #pragma unroll
        for (int j = 0; j < 16; ++j) {
            float2 v = sv[padslot(base2 + (j << 4))];
            ar[j] = v.x; ai[j] = v.y;
        }
        #pragma unroll
        for (int b = 0; b < 4; ++b) {
            const int m = 1 << b;
            const float c = cs_c[4 + b], s = cs_s[4 + b];
            #pragma unroll
            for (int j = 0; j < 16; ++j)
                if (!(j & m)) rotg(ar[j], ai[j], ar[j | m], ai[j | m], c, s);
        }
        #pragma unroll
        for (int j = 0; j < 16; ++j)
            sv[padslot(base2 + (j << 4))] = make_float2(ar[j], ai[j]);
    }
    __syncthreads();

    // A3: reg bits {0..3}, then coalesced float4 stores
    {
        const int base3 = t << 4;
        #pragma unroll
        for (int j = 0; j < 16; ++j) {
            float2 v = sv[padslot(base3 + j)];
            ar[j] = v.x; ai[j] = v.y;
        }
        #pragma unroll
        for (int b = 0; b < 4; ++b) {
            const int m = 1 << b;
            const float c = cs_c[b], s = cs_s[b];
            #pragma unroll
            for (int j = 0; j < 16; ++j)
                if (!(j & m)) rotg(ar[j], ai[j], ar[j | m], ai[j | m], c, s);
        }
        float4* orp = (float4*)(out + g0 + base3);
        float4* oip = (float4*)(out + NTOT + g0 + base3);
        #pragma unroll
        for (int q = 0; q < 4; ++q) {
            orp[q] = make_float4(ar[4*q], ar[4*q+1], ar[4*q+2], ar[4*q+3]);
            oip[q] = make_float4(ai[4*q], ai[4*q+1], ai[4*q+2], ai[4*q+3]);
        }
    }
}

// ---------------- P2: bits 12..21, 1024 rows (stride 4096) x 16 cols ------
// 1024 threads, 16 complex/thread: c = t&15 (col), q = t>>4 (row group).
//  arr1 (load):  h = q + 64*j        -> j = h bits {6..9}, gates 18-21
//  arr2:         h = (q&3) + 64*(q>>2) + 4*j -> j = h bits {2..5}, gates 14-17
//  arr3 (store): h = 16*q + j        -> j = h bits {0..3}, gates 12-13 (on j&3)
// LDS: separate sr/si float arrays, row stride 17 -> <=2-way bank aliasing
// in all arrangements (verified by hand: 17*q mod 32 spreads the 4 row-lanes).
// Global: every access is 4 x 64 B contiguous row segments per wave-instr.
__global__ __launch_bounds__(1024, 4) void rgate_hi(const float* __restrict__ ang,
                                                    float* __restrict__ out) {
    extern __shared__ float lds[];
    float* sr = lds;            // 1024*17 floats
    float* si = lds + 17408;    // 1024*17 floats
    __shared__ float csc[22], css[22];
    const int t    = threadIdx.x;
    const int c    = t & 15;
    const int q    = t >> 4;            // [0,64)
    const int col0 = (blockIdx.x << 4) + c;

    if (t < 22) { float a = 0.5f * ang[21 - t]; csc[t] = cosf(a); css[t] = sinf(a); }

    float vr[16], vi[16];
    #pragma unroll
    for (int j = 0; j < 16; ++j) {
        const int g = ((q + (j << 6)) << 12) + col0;
        vr[j] = out[g]; vi[j] = out[NTOT + g];
    }
    __syncthreads();   // csc ready

    // gates 18..21 on j (h bits 6..9)
    #pragma unroll
    for (int b = 0; b < 4; ++b) {
        const int m = 1 << b;
        const float cc = csc[18 + b], ss = css[18 + b];
        #pragma unroll
        for (int j = 0; j < 16; ++j)
            if (!(j & m)) rotg(vr[j], vi[j], vr[j | m], vi[j | m], cc, ss);
    }
    #pragma unroll
    for (int j = 0; j < 16; ++j) {
        const int h = q + (j << 6);
        sr[h * 17 + c] = vr[j]; si[h * 17 + c] = vi[j];
    }
    __syncthreads();

    // arr2: h bits {2..5} in regs -> gates 14..17
    {
        const int hb = (q & 3) + ((q >> 2) << 6);
        #pragma unroll
        for (int j = 0; j < 16; ++j) {
            const int h = hb + (j << 2);
            vr[j] = sr[h * 17 + c]; vi[j] = si[h * 17 + c];
        }
        #pragma unroll
        for (int b = 0; b < 4; ++b) {
            const int m = 1 << b;
            const float cc = csc[14 + b], ss = css[14 + b];
            #pragma unroll
            for (int j = 0; j < 16; ++j)
                if (!(j & m)) rotg(vr[j], vi[j], vr[j | m], vi[j | m], cc, ss);
        }
        #pragma unroll
        for (int j = 0; j < 16; ++j) {
            const int h = hb + (j << 2);
            sr[h * 17 + c] = vr[j]; si[h * 17 + c] = vi[j];
        }
    }
    __syncthreads();

    // arr3: h bits {0..3} in regs -> gates 12,13 on (j&3), then store
    {
        #pragma unroll
        for (int j = 0; j < 16; ++j) {
            const int h = (q << 4) + j;
            vr[j] = sr[h * 17 + c]; vi[j] = si[h * 17 + c];
        }
        #pragma unroll
        for (int b = 0; b < 2; ++b) {
            const int m = 1 << b;
            const float cc = csc[12 + b], ss = css[12 + b];
            #pragma unroll
            for (int j = 0; j < 16; ++j)
                if (!(j & m)) rotg(vr[j], vi[j], vr[j | m], vi[j | m], cc, ss);
        }
        #pragma unroll
        for (int j = 0; j < 16; ++j) {
            const int g = (((q << 4) + j) << 12) + col0;
            out[g] = vr[j]; out[NTOT + g] = vi[j];
        }
    }
}

extern "C" void kernel_launch(void* const* d_in, const int* in_sizes, int n_in,
                              void* d_out, int out_size, void* d_ws, size_t ws_size,
                              hipStream_t stream) {
    const float* xr  = (const float*)d_in[0];
    const float* xi  = (const float*)d_in[1];
    const float* ang = (const float*)d_in[2];
    float* out = (float*)d_out;

    // P2 needs 2*1024*17*4 = 139264 B dynamic LDS (> 64 KB default cap)
    static_assert(2 * 1024 * 17 * 4 == 139264, "");
    hipFuncSetAttribute((const void*)rgate_hi,
                        hipFuncAttributeMaxDynamicSharedMemorySize, 139264);

    // P1: bits 0-11, d_in -> d_out (fully overwrites d_out)
    rgate_low<<<1024, 256, 0, stream>>>(xr, xi, ang, out);
    // P2: bits 12-21, in-place on d_out
    rgate_hi<<<256, 1024, 139264, stream>>>(ang, out);
}